// Round 1
// baseline (101.880 us; speedup 1.0000x reference)
//
#include <hip/hip_runtime.h>
#include <hip/hip_bf16.h>

#define NN 4096
#define DD 128
#define CC 20
#define NSPLIT 8
#define COLS_PER_SPLIT (NN / NSPLIT)   // 512
#define ROWS_PER_BLOCK 16
#define NSTRIP (NN / ROWS_PER_BLOCK)   // 256
#define BSTRIDE 152                    // ushorts per LDS B-tile row (128 + 24 pad; 304B, 16B-aligned, bank-spread)

typedef __attribute__((ext_vector_type(8))) short short8;
typedef __attribute__((ext_vector_type(4))) float floatx4;

// ---------------- K1: row-normalize + bf16 convert ----------------
__global__ void k_normalize(const float* __restrict__ x, __hip_bfloat16* __restrict__ out) {
    int wave = threadIdx.x >> 6;
    int lane = threadIdx.x & 63;
    int row  = blockIdx.x * 4 + wave;
    const float* xr = x + (size_t)row * DD;
    float2 v = *(const float2*)(xr + lane * 2);
    float ss = v.x * v.x + v.y * v.y;
    #pragma unroll
    for (int m = 1; m <= 32; m <<= 1) ss += __shfl_xor(ss, m);
    float nrm = sqrtf(ss);
    float inv = 1.0f / fmaxf(nrm, 1e-12f);
    __hip_bfloat162 h;
    h.x = __float2bfloat16(v.x * inv);
    h.y = __float2bfloat16(v.y * inv);
    *(__hip_bfloat162*)(out + (size_t)row * DD + lane * 2) = h;
}

// ---------------- K2: fused Gram + per-row stats ----------------
// Per row i (split over col ranges):
//   E1 = sum_{same,j!=i} exp(10*G - 10), T1 = sum_{same,j!=i} 10*G, C1 = count
//   m2 = max(0, max_{diff} 20*G),  E2 = sum_{diff} exp(20*G - m2)
__launch_bounds__(64, 2)
__global__ void k_gram_stats(const __hip_bfloat16* __restrict__ feats,
                             const int* __restrict__ tgt,
                             float* __restrict__ E1p, float* __restrict__ T1p,
                             float* __restrict__ C1p, float* __restrict__ m2p,
                             float* __restrict__ E2p) {
    __shared__ __align__(16) unsigned short Bt[64 * BSTRIDE];
    int lane  = threadIdx.x;                 // 0..63
    int strip = blockIdx.x & (NSTRIP - 1);   // 256 strips of 16 rows
    int split = blockIdx.x >> 8;             // 8 col splits of 512
    int rbase  = strip * ROWS_PER_BLOCK;
    int cbase0 = split * COLS_PER_SPLIT;
    int lr = lane & 15, lk = lane >> 4;

    // A fragments: rows rbase+lr, k-chunks of 32 (lane slot k = kc*32 + lk*8 + j)
    short8 afrag[4];
    const __hip_bfloat16* arow = feats + (size_t)(rbase + lr) * DD;
    #pragma unroll
    for (int kc = 0; kc < 4; ++kc)
        afrag[kc] = *(const short8*)(arow + kc * 32 + lk * 8);

    // stats rows owned by this lane (C/D layout: row = lk*4+q, col = lr)
    int rl[4], gr[4];
    #pragma unroll
    for (int q = 0; q < 4; ++q) { gr[q] = rbase + lk * 4 + q; rl[q] = tgt[gr[q]]; }

    float E1[4] = {0,0,0,0}, T1[4] = {0,0,0,0}, C1[4] = {0,0,0,0};
    float m2[4] = {0,0,0,0}, E2[4] = {0,0,0,0};

    for (int t = 0; t < COLS_PER_SPLIT / 64; ++t) {
        int cbase = cbase0 + t * 64;
        // stage B tile: 64 feat-rows (G cols) x 128 k, coalesced 16B chunks
        #pragma unroll
        for (int i = 0; i < 16; ++i) {
            int idx = lane + i * 64;
            int row = idx >> 4, ch = idx & 15;
            *(floatx4*)(&Bt[row * BSTRIDE + ch * 8]) =
                *(const floatx4*)(feats + (size_t)(cbase + row) * DD + ch * 8);
        }
        __syncthreads();
        #pragma unroll
        for (int sc = 0; sc < 4; ++sc) {
            floatx4 acc = {0.0f, 0.0f, 0.0f, 0.0f};
            #pragma unroll
            for (int kc = 0; kc < 4; ++kc) {
                short8 b = *(const short8*)(&Bt[(sc * 16 + lr) * BSTRIDE + kc * 32 + lk * 8]);
                acc = __builtin_amdgcn_mfma_f32_16x16x32_bf16(afrag[kc], b, acc, 0, 0, 0);
            }
            int gc   = cbase + sc * 16 + lr;
            int clab = tgt[gc];
            #pragma unroll
            for (int q = 0; q < 4; ++q) {
                float g = acc[q];
                bool same = (rl[q] == clab);
                bool v1   = same && (gr[q] != gc);
                float l1 = g * 10.0f;           // 1/TEMP
                float l2 = g * 20.0f;           // 1/TEMP2
                float l1v = v1 ? l1 : -__builtin_inff();
                E1[q] += __expf(l1v - 10.0f);   // fixed reference R=10 (max cancels)
                T1[q] += v1 ? l1 : 0.0f;
                C1[q] += v1 ? 1.0f : 0.0f;
                // online-max for triple term (branchless)
                float l2v = same ? -__builtin_inff() : l2;
                float nm  = fmaxf(m2[q], l2v);
                E2[q] = E2[q] * __expf(m2[q] - nm) + __expf(l2v - nm);
                m2[q] = nm;
            }
        }
        __syncthreads();
    }

    // merge across the 16 lanes of each row-group
    #pragma unroll
    for (int q = 0; q < 4; ++q) {
        float e1 = E1[q], t1 = T1[q], c1 = C1[q], mm = m2[q], e2 = E2[q];
        #pragma unroll
        for (int m = 1; m <= 8; m <<= 1) {
            e1 += __shfl_xor(e1, m);
            t1 += __shfl_xor(t1, m);
            c1 += __shfl_xor(c1, m);
            float om = __shfl_xor(mm, m), oe = __shfl_xor(e2, m);
            float nm = fmaxf(mm, om);
            e2 = e2 * __expf(mm - nm) + oe * __expf(om - nm);
            mm = nm;
        }
        if (lr == 0) {
            int r = gr[q];
            E1p[split * NN + r] = e1;
            T1p[split * NN + r] = t1;
            C1p[split * NN + r] = c1;
            m2p[split * NN + r] = mm;
            E2p[split * NN + r] = e2;
        }
    }
}

// ---------------- K3: finalize (single block) ----------------
#define FT 1024
__global__ void k_finalize(const float* __restrict__ predicts, const int* __restrict__ tgt,
                           const float* __restrict__ E1p, const float* __restrict__ T1p,
                           const float* __restrict__ C1p, const float* __restrict__ m2p,
                           const float* __restrict__ E2p, float* __restrict__ out) {
    __shared__ int   hist[CC];
    __shared__ float Rt[CC];
    __shared__ float sred[FT];
    __shared__ float s_cl;
    int t = threadIdx.x;
    if (t < CC) { hist[t] = 0; Rt[t] = 0.0f; }
    __syncthreads();
    for (int r = t; r < NN; r += FT) atomicAdd(&hist[tgt[r]], 1);
    __syncthreads();

    float clsum = 0.0f, cesum = 0.0f;
    for (int r = t; r < NN; r += FT) {
        int tg = tgt[r];
        float e1 = 0.0f, t1 = 0.0f, c1 = 0.0f, mg = 0.0f;
        float mv[NSPLIT], ev[NSPLIT];
        #pragma unroll
        for (int s = 0; s < NSPLIT; ++s) {
            e1 += E1p[s * NN + r];
            t1 += T1p[s * NN + r];
            c1 += C1p[s * NN + r];
            mv[s] = m2p[s * NN + r];
            ev[s] = E2p[s * NN + r];
            mg = fmaxf(mg, mv[s]);
        }
        float e2 = 0.0f;
        #pragma unroll
        for (int s = 0; s < NSPLIT; ++s) e2 += ev[s] * __expf(mv[s] - mg);

        if (c1 > 0.0f) clsum += (t1 - c1 * (10.0f + logf(e1))) / c1;

        float rj = (float)hist[tg] * __expf(-mg) + e2;   // r_j of nt_xent_loss2
        atomicAdd(&Rt[tg], rj);

        const float* p = predicts + (size_t)r * CC;
        float mx = p[0];
        #pragma unroll
        for (int j = 1; j < CC; ++j) mx = fmaxf(mx, p[j]);
        float se = 0.0f;
        #pragma unroll
        for (int j = 0; j < CC; ++j) se += __expf(p[j] - mx);
        cesum += mx + logf(se) - p[tg];
    }

    sred[t] = clsum; __syncthreads();
    for (int off = FT / 2; off > 0; off >>= 1) {
        if (t < off) sred[t] += sred[t + off];
        __syncthreads();
    }
    if (t == 0) s_cl = sred[0];
    __syncthreads();
    sred[t] = cesum; __syncthreads();
    for (int off = FT / 2; off > 0; off >>= 1) {
        if (t < off) sred[t] += sred[t + off];
        __syncthreads();
    }
    if (t == 0) {
        float ce = sred[0] / (float)NN;
        float cl = -s_cl / (float)NN;
        float Rtot = 0.0f;
        long long Ctot = 0;
        for (int k = 0; k < CC; ++k) {
            Rtot += Rt[k];
            Ctot += (long long)hist[k] * (NN - hist[k]);
        }
        bool all_zero = true;
        for (int k = 0; k < CC; ++k)
            if (hist[k] > 0 && (Ctot - (long long)hist[k] * (NN - hist[k])) != 0) all_zero = false;
        float trip = 0.0f;
        for (int k = 0; k < CC; ++k) {
            if (hist[k] == 0) continue;
            long long c = NN - hist[k];
            float S = (c > 0) ? (Rtot - Rt[k] + (float)hist[k] * (float)NN) : 0.0f;
            long long ns = Ctot - (long long)hist[k] * (NN - hist[k]);
            float x = all_zero ? S : S / (float)(ns == 0 ? 1 : ns);
            trip += (float)hist[k] * logf(x + 1e-12f);
        }
        float triple = trip / (float)NN;   // = -mean(pos_logits)
        out[0] = 0.5f * ce + 0.5f * cl + 0.25f * triple;
    }
}

extern "C" void kernel_launch(void* const* d_in, const int* in_sizes, int n_in,
                              void* d_out, int out_size, void* d_ws, size_t ws_size,
                              hipStream_t stream) {
    const float* cls  = (const float*)d_in[0];
    const float* pred = (const float*)d_in[1];
    const int*   tgt  = (const int*)d_in[2];
    float* out = (float*)d_out;
    char* ws = (char*)d_ws;

    __hip_bfloat16* feats = (__hip_bfloat16*)ws;            // 1 MB
    float* E1p = (float*)(ws + 1048576);                    // 8*4096*4 each
    float* T1p = E1p + (size_t)NSPLIT * NN;
    float* C1p = T1p + (size_t)NSPLIT * NN;
    float* m2p = C1p + (size_t)NSPLIT * NN;
    float* E2p = m2p + (size_t)NSPLIT * NN;

    hipLaunchKernelGGL(k_normalize, dim3(NN / 4), dim3(256), 0, stream, cls, feats);
    hipLaunchKernelGGL(k_gram_stats, dim3(NSTRIP * NSPLIT), dim3(64), 0, stream,
                       feats, tgt, E1p, T1p, C1p, m2p, E2p);
    hipLaunchKernelGGL(k_finalize, dim3(1), dim3(FT), 0, stream,
                       pred, tgt, E1p, T1p, C1p, m2p, E2p, out);
}

// Round 2
// 94.598 us; speedup vs baseline: 1.0770x; 1.0770x over previous
//
#include <hip/hip_runtime.h>
#include <hip/hip_bf16.h>

#define NN 4096
#define DD 128
#define CC 20
#define NSPLIT 16
#define CPS (NN / NSPLIT)             // 256 cols per split
#define ROWS_PER_WAVE 16
#define ROWS_PER_BLOCK 64             // 4 waves x 16 rows
#define NSTRIP (NN / ROWS_PER_BLOCK)  // 64
#define BSTRIDE 152                   // ushorts per LDS B row (128 + 24 pad)

typedef __attribute__((ext_vector_type(8))) short short8;
typedef __attribute__((ext_vector_type(4))) float floatx4;

// ---------------- K1: normalize + bf16, CE partials, zero stats ----------------
__global__ void k_prep(const float* __restrict__ x, const float* __restrict__ pred,
                       const int* __restrict__ tgt,
                       __hip_bfloat16* __restrict__ feats,
                       float* __restrict__ statsz,   // 4*NN floats, zeroed here
                       float* __restrict__ ce_part) {
    __shared__ float ce_w[4];
    int wave = threadIdx.x >> 6, lane = threadIdx.x & 63;
    int row = blockIdx.x * 4 + wave;
    // zero the 4 stat arrays: 1024 blocks x 16 floats = 16384 = 4*4096
    if (threadIdx.x < 16) statsz[blockIdx.x * 16 + threadIdx.x] = 0.0f;
    // row-normalize cls_feats -> bf16
    const float* xr = x + (size_t)row * DD;
    float2 v = *(const float2*)(xr + lane * 2);
    float ss = v.x * v.x + v.y * v.y;
    #pragma unroll
    for (int m = 1; m <= 32; m <<= 1) ss += __shfl_xor(ss, m);
    float inv = 1.0f / fmaxf(sqrtf(ss), 1e-12f);
    __hip_bfloat162 h;
    h.x = __float2bfloat16(v.x * inv);
    h.y = __float2bfloat16(v.y * inv);
    *(__hip_bfloat162*)(feats + (size_t)row * DD + lane * 2) = h;
    // CE for predicts row (lanes 0..19 hold logits)
    float p = (lane < CC) ? pred[(size_t)row * CC + lane] : -__builtin_inff();
    float mx = p;
    #pragma unroll
    for (int m = 1; m <= 32; m <<= 1) mx = fmaxf(mx, __shfl_xor(mx, m));
    float e = (lane < CC) ? __expf(p - mx) : 0.0f;
    #pragma unroll
    for (int m = 1; m <= 32; m <<= 1) e += __shfl_xor(e, m);
    float ptg = __shfl(p, tgt[row]);
    if (lane == 0) ce_w[wave] = mx + logf(e) - ptg;
    __syncthreads();
    if (threadIdx.x == 0)
        ce_part[blockIdx.x] = ce_w[0] + ce_w[1] + ce_w[2] + ce_w[3];
}

// ---------------- K2: fused Gram + per-row stats ----------------
// Per row i: E1 = sum_{same,j!=i} exp(10G-10), T1 = sum 10G, (count from hist)
//            m2 = max(0, max_diff 20G), E2f = sum_diff exp(20G-20)  [fixed ref]
// exp(20G-20) = exp(10G-10)^2 -> single exp per element, no loop-carried rescale.
__launch_bounds__(256, 4)
__global__ void k_gram_stats(const __hip_bfloat16* __restrict__ feats,
                             const int* __restrict__ tgt,
                             float* __restrict__ E1g, float* __restrict__ T1g,
                             float* __restrict__ E2g, float* __restrict__ M2g) {
    __shared__ __align__(16) unsigned short Bt[64 * BSTRIDE];
    int lane  = threadIdx.x & 63;
    int wave  = threadIdx.x >> 6;
    int strip = blockIdx.x & (NSTRIP - 1);
    int split = blockIdx.x >> 6;
    int rbase  = strip * ROWS_PER_BLOCK + wave * ROWS_PER_WAVE;
    int cbase0 = split * CPS;
    int lr = lane & 15, lk = lane >> 4;

    // A fragments: rows rbase+lr, k = kc*32 + lk*8 + j (same map as B -> valid)
    short8 afrag[4];
    const __hip_bfloat16* arow = feats + (size_t)(rbase + lr) * DD;
    #pragma unroll
    for (int kc = 0; kc < 4; ++kc)
        afrag[kc] = *(const short8*)(arow + kc * 32 + lk * 8);

    int rl[4], gr[4];
    #pragma unroll
    for (int q = 0; q < 4; ++q) { gr[q] = rbase + lk * 4 + q; rl[q] = tgt[gr[q]]; }

    float E1[4] = {0,0,0,0}, T1[4] = {0,0,0,0}, E2[4] = {0,0,0,0}, m2[4] = {0,0,0,0};

    for (int t = 0; t < CPS / 64; ++t) {
        int cbase = cbase0 + t * 64;
        // stage B tile: 64 rows x 128 k bf16, 4 passes of 256 threads x 16B
        #pragma unroll
        for (int i = 0; i < 4; ++i) {
            int idx = threadIdx.x + i * 256;
            int row = idx >> 4, ch = idx & 15;
            *(floatx4*)(&Bt[row * BSTRIDE + ch * 8]) =
                *(const floatx4*)(feats + (size_t)(cbase + row) * DD + ch * 8);
        }
        __syncthreads();
        #pragma unroll
        for (int sc = 0; sc < 4; ++sc) {
            floatx4 acc = {0.0f, 0.0f, 0.0f, 0.0f};
            #pragma unroll
            for (int kc = 0; kc < 4; ++kc) {
                short8 b = *(const short8*)(&Bt[(sc * 16 + lr) * BSTRIDE + kc * 32 + lk * 8]);
                acc = __builtin_amdgcn_mfma_f32_16x16x32_bf16(afrag[kc], b, acc, 0, 0, 0);
            }
            int gc   = cbase + sc * 16 + lr;
            int clab = tgt[gc];
            #pragma unroll
            for (int q = 0; q < 4; ++q) {
                float g  = acc[q];
                float l1 = g * 10.0f;
                float tv = __expf(l1 - 10.0f);
                bool same = (rl[q] == clab);
                bool v1   = same && (gr[q] != gc);
                E1[q] += v1 ? tv : 0.0f;
                T1[q] += v1 ? l1 : 0.0f;
                E2[q] += same ? 0.0f : tv * tv;
                m2[q] = fmaxf(m2[q], same ? 0.0f : l1 + l1);
            }
        }
        __syncthreads();
    }

    // merge across the 16 lanes (lr) of each row-group; then global atomics
    #pragma unroll
    for (int q = 0; q < 4; ++q) {
        float e1 = E1[q], t1 = T1[q], e2 = E2[q], mm = m2[q];
        #pragma unroll
        for (int m = 1; m <= 8; m <<= 1) {
            e1 += __shfl_xor(e1, m);
            t1 += __shfl_xor(t1, m);
            e2 += __shfl_xor(e2, m);
            mm = fmaxf(mm, __shfl_xor(mm, m));
        }
        if (lr == 0) {
            int r = gr[q];
            atomicAdd(&E1g[r], e1);
            atomicAdd(&T1g[r], t1);
            atomicAdd(&E2g[r], e2);
            atomicMax((int*)&M2g[r], __float_as_int(mm));  // mm >= 0: int-bit order ok
        }
    }
}

// ---------------- K3: finalize (single block) ----------------
#define FT 256
__global__ void k_finalize(const int* __restrict__ tgt,
                           const float* __restrict__ E1g, const float* __restrict__ T1g,
                           const float* __restrict__ E2g, const float* __restrict__ M2g,
                           const float* __restrict__ ce_part, float* __restrict__ out) {
    __shared__ int   hist[CC];
    __shared__ float Rt[CC];
    __shared__ float red[FT];
    __shared__ float s_cl;
    int t = threadIdx.x;
    if (t < CC) { hist[t] = 0; Rt[t] = 0.0f; }
    __syncthreads();
    for (int r = t; r < NN; r += FT) atomicAdd(&hist[tgt[r]], 1);
    __syncthreads();

    float clsum = 0.0f;
    for (int r = t; r < NN; r += FT) {
        int tg = tgt[r];
        int h  = hist[tg];
        float c1 = (float)(h - 1);
        float e1 = E1g[r], t1 = T1g[r], e2 = E2g[r], m = M2g[r];
        if (c1 > 0.0f) clsum += (t1 - c1 * (10.0f + logf(e1))) / c1;
        float rj = (float)h * __expf(-m) + e2 * __expf(20.0f - m);
        atomicAdd(&Rt[tg], rj);
    }
    float cesum = 0.0f;
    for (int i = t; i < 1024; i += FT) cesum += ce_part[i];

    red[t] = clsum; __syncthreads();
    for (int off = FT / 2; off; off >>= 1) {
        if (t < off) red[t] += red[t + off];
        __syncthreads();
    }
    if (t == 0) s_cl = red[0];
    __syncthreads();
    red[t] = cesum; __syncthreads();
    for (int off = FT / 2; off; off >>= 1) {
        if (t < off) red[t] += red[t + off];
        __syncthreads();
    }
    if (t == 0) {
        float ce = red[0] / (float)NN;
        float cl = -s_cl / (float)NN;
        float Rtot = 0.0f;
        long long Ctot = 0;
        for (int k = 0; k < CC; ++k) {
            Rtot += Rt[k];
            Ctot += (long long)hist[k] * (NN - hist[k]);
        }
        bool all_zero = true;
        for (int k = 0; k < CC; ++k)
            if (hist[k] > 0 && (Ctot - (long long)hist[k] * (NN - hist[k])) != 0) all_zero = false;
        float trip = 0.0f;
        for (int k = 0; k < CC; ++k) {
            if (hist[k] == 0) continue;
            long long c = NN - hist[k];
            float S = (c > 0) ? (Rtot - Rt[k] + (float)hist[k] * (float)NN) : 0.0f;
            long long ns = Ctot - (long long)hist[k] * (NN - hist[k]);
            float x = all_zero ? S : S / (float)(ns == 0 ? 1 : ns);
            trip += (float)hist[k] * logf(x + 1e-12f);
        }
        float triple = trip / (float)NN;
        out[0] = 0.5f * ce + 0.5f * cl + 0.25f * triple;
    }
}

extern "C" void kernel_launch(void* const* d_in, const int* in_sizes, int n_in,
                              void* d_out, int out_size, void* d_ws, size_t ws_size,
                              hipStream_t stream) {
    const float* cls  = (const float*)d_in[0];
    const float* pred = (const float*)d_in[1];
    const int*   tgt  = (const int*)d_in[2];
    float* out = (float*)d_out;
    char* ws = (char*)d_ws;

    __hip_bfloat16* feats = (__hip_bfloat16*)ws;            // 1 MB
    float* stats = (float*)(ws + 1048576);                  // 4*4096 floats
    float* E1g = stats;
    float* T1g = stats + NN;
    float* E2g = stats + 2 * NN;
    float* M2g = stats + 3 * NN;
    float* ce_part = stats + 4 * NN;                        // 1024 floats

    hipLaunchKernelGGL(k_prep, dim3(NN / 4), dim3(256), 0, stream,
                       cls, pred, tgt, feats, stats, ce_part);
    hipLaunchKernelGGL(k_gram_stats, dim3(NSTRIP * NSPLIT), dim3(256), 0, stream,
                       feats, tgt, E1g, T1g, E2g, M2g);
    hipLaunchKernelGGL(k_finalize, dim3(1), dim3(FT), 0, stream,
                       tgt, E1g, T1g, E2g, M2g, ce_part, out);
}